// Round 5
// baseline (736.582 us; speedup 1.0000x reference)
//
#include <hip/hip_runtime.h>
#include <hip/hip_bf16.h>

static constexpr int NN = 1000000;   // nodes
static constexpr int NE = 5000000;   // edges
static constexpr int NG = 4096;      // graphs
static constexpr int NB = (NN + 1023) >> 10;          // 977 bins of 1024 consecutive nodes
static constexpr int EPB = 16384;                     // edges per block for binning passes
static constexpr int BIN_BLOCKS = (NE + EPB - 1) / EPB;  // 306

// transform(x) == tanh(x) for finite x (nan_to_num / clip are no-ops on tanh output)
__device__ __forceinline__ float fast_tanh(float x) {
    x = fminf(fmaxf(x, -10.0f), 10.0f);
    float e = __expf(2.0f * x);
    return (e - 1.0f) / (e + 1.0f);
}

// ---- Pass 1: per-bin edge counts (LDS histogram, 1 global atomic per block-bin) ----
__global__ __launch_bounds__(256) void bin_hist_k(
    const int* __restrict__ row, int* __restrict__ binCount)
{
    __shared__ int hist[NB];
    for (int i = threadIdx.x; i < NB; i += 256) hist[i] = 0;
    __syncthreads();
    int base = blockIdx.x * EPB;
#pragma unroll 4
    for (int k = 0; k < EPB / 256; ++k) {
        int e = base + k * 256 + threadIdx.x;
        if (e < NE) atomicAdd(&hist[row[e] >> 10], 1);
    }
    __syncthreads();
    for (int i = threadIdx.x; i < NB; i += 256) {
        int c = hist[i];
        if (c) atomicAdd(&binCount[i], c);
    }
}

// ---- Pass 2: exclusive scan of binCount -> binStart, binCursor ----
__global__ __launch_bounds__(1024) void bin_scan_k(
    const int* __restrict__ binCount, int* __restrict__ binStart, int* __restrict__ binCursor)
{
    __shared__ int s[1024];
    int t = threadIdx.x;
    int v = (t < NB) ? binCount[t] : 0;
    s[t] = v;
    __syncthreads();
    for (int off = 1; off < 1024; off <<= 1) {
        int u = (t >= off) ? s[t - off] : 0;
        __syncthreads();
        s[t] += u;
        __syncthreads();
    }
    if (t < NB) { int ex = s[t] - v; binStart[t] = ex; binCursor[t] = ex; }
    if (t == 0) binStart[NB] = NE;
}

// ---- Pass 3: scatter x-triplet + local row into bin-grouped order ----
// Per block: LDS hist, reserve one global range per touched bin, then write.
// Same-bin edges within a block land contiguously -> no 64B-line amplification.
__global__ __launch_bounds__(256) void bin_scatter_k(
    const int* __restrict__ row, const int* __restrict__ col,
    const float* __restrict__ x, int* __restrict__ binCursor,
    float* __restrict__ sx, unsigned short* __restrict__ srow)
{
    __shared__ int hist[NB];
    for (int i = threadIdx.x; i < NB; i += 256) hist[i] = 0;
    __syncthreads();
    int base = blockIdx.x * EPB;
#pragma unroll 4
    for (int k = 0; k < EPB / 256; ++k) {
        int e = base + k * 256 + threadIdx.x;
        if (e < NE) atomicAdd(&hist[row[e] >> 10], 1);
    }
    __syncthreads();
    // hist[bin] becomes this block's global write cursor for that bin
    for (int i = threadIdx.x; i < NB; i += 256) {
        int c = hist[i];
        hist[i] = c ? atomicAdd(&binCursor[i], c) : 0;
    }
    __syncthreads();
#pragma unroll 4
    for (int k = 0; k < EPB / 256; ++k) {
        int e = base + k * 256 + threadIdx.x;
        if (e >= NE) continue;
        int r = row[e];
        int c = col[e];
        int pos = atomicAdd(&hist[r >> 10], 1);
        float x0 = x[3 * c + 0], x1 = x[3 * c + 1], x2 = x[3 * c + 2];
        size_t p3 = 3 * (size_t)pos;
        sx[p3 + 0] = x0; sx[p3 + 1] = x1; sx[p3 + 2] = x2;
        srow[pos] = (unsigned short)(r & 1023);
    }
}

// ---- Pass 4: per-bucket LDS aggregation + MLP2 + segmented-scan pooling ----
__global__ __launch_bounds__(256) void bucket_agg_k(
    const float* __restrict__ sx,
    const unsigned short* __restrict__ srow,
    const int* __restrict__ binStart,
    const int* __restrict__ batch,
    const float* __restrict__ w1,   // [3,16]
    const float* __restrict__ b1,   // [16]
    const float* __restrict__ w2,   // [16,16]
    const float* __restrict__ b2,   // [16]
    float* __restrict__ h_sum,      // [NG,16]
    unsigned int* __restrict__ h_max, // [NG,16] monotone-encoded
    int* __restrict__ cnt)          // [NG]
{
    extern __shared__ char smem[];
    float* agg = (float*)smem;                       // [1024][17] padded
    int* degs  = (int*)(smem + 1024 * 17 * 4);       // [1024]

    for (int i = threadIdx.x; i < 1024 * 17; i += 256) agg[i] = 0.0f;
    for (int i = threadIdx.x; i < 1024; i += 256) degs[i] = 0;
    __syncthreads();

    int b = blockIdx.x;
    int nodeBase = b << 10;
    int nNodes = min(1024, NN - nodeBase);           // 1024, or 576 for the last bin (%64==0)
    int es = binStart[b], ee = binStart[b + 1];

    // edge phase: recompute h1 on the fly, LDS-atomic accumulate
    for (int i = es + threadIdx.x; i < ee; i += 256) {
        size_t p3 = 3 * (size_t)i;
        float x0 = sx[p3 + 0], x1 = sx[p3 + 1], x2 = sx[p3 + 2];
        int rl = srow[i];
        atomicAdd(&degs[rl], 1);
        int aoff = rl * 17;
#pragma unroll
        for (int j = 0; j < 16; ++j) {
            float v = fmaf(x2, w1[32 + j], fmaf(x1, w1[16 + j], fmaf(x0, w1[j], b1[j])));
            atomicAdd(&agg[aoff + j], fast_tanh(v));
        }
    }
    __syncthreads();

    // node phase: normalize, MLP2, tanh, segmented wave reduction over sorted batch
    for (int nb = 0; nb < nNodes; nb += 256) {
        int node = nb + threadIdx.x;
        if (node >= nNodes) continue;                // wave-uniform (nNodes % 64 == 0)
        int dg = degs[node];
        float inv = 1.0f / fmaxf((float)dg, 1.0f);
        float s[16];
#pragma unroll
        for (int j = 0; j < 16; ++j) s[j] = b2[j];
#pragma unroll
        for (int k = 0; k < 16; ++k) {
            float a = agg[node * 17 + k] * inv;
#pragma unroll
            for (int j = 0; j < 16; ++j) s[j] = fmaf(a, w2[16 * k + j], s[j]);
        }
        float m[16];
#pragma unroll
        for (int j = 0; j < 16; ++j) { s[j] = fast_tanh(s[j]); m[j] = s[j]; }

        int g = batch[nodeBase + node];
        int lane = threadIdx.x & 63;
        int gp = __shfl_up(g, 1);
        int head = (lane == 0) || (g != gp);
        unsigned long long hm = __ballot(head != 0);

        int f = head;
#pragma unroll
        for (int off = 1; off < 64; off <<= 1) {
            int fu = __shfl_up(f, off);
            bool take = (lane >= off) && (f == 0);
#pragma unroll
            for (int j = 0; j < 16; ++j) {
                float su = __shfl_up(s[j], off);
                float mu = __shfl_up(m[j], off);
                if (take) { s[j] += su; m[j] = fmaxf(m[j], mu); }
            }
            if (lane >= off) f |= fu;
        }

        int hnext = __shfl_down(head, 1);
        bool is_last = (lane == 63) || (hnext != 0);
        if (is_last) {
            unsigned long long below = hm & (~0ULL >> (63 - lane));
            int start = 63 - __clzll(below);
            int seglen = lane - start + 1;
#pragma unroll
            for (int j = 0; j < 16; ++j) {
                unsafeAtomicAdd(&h_sum[16 * g + j], s[j]);
                atomicMax(&h_max[16 * g + j], __float_as_uint(m[j] + 2.0f));
            }
            atomicAdd(&cnt[g], seglen);
        }
    }
}

// ---- Pass 5: head ----
__global__ __launch_bounds__(256) void out_k(
    const float* __restrict__ h_sum,
    const unsigned int* __restrict__ h_max,
    const int* __restrict__ cnt,
    const float* __restrict__ w3,   // [32]
    const float* __restrict__ b3,   // [1]
    float* __restrict__ out)        // [NG]
{
    int g = blockIdx.x * 256 + threadIdx.x;
    if (g >= NG) return;
    float invc = 1.0f / fmaxf((float)cnt[g], 1.0f);
    float acc = b3[0];
#pragma unroll
    for (int j = 0; j < 16; ++j) {
        float mean = h_sum[16 * g + j] * invc;
        unsigned int e = h_max[16 * g + j];
        float mx = (e == 0u) ? 0.0f : (__uint_as_float(e) - 2.0f);
        acc = fmaf(mean, w3[j], fmaf(mx, w3[16 + j], acc));
    }
    out[g] = 1.0f / (1.0f + __expf(-acc));
}

extern "C" void kernel_launch(void* const* d_in, const int* in_sizes, int n_in,
                              void* d_out, int out_size, void* d_ws, size_t ws_size,
                              hipStream_t stream)
{
    const float* x   = (const float*)d_in[0];
    const int*   ei  = (const int*)d_in[1];   // row = ei, col = ei + NE
    const int*   bat = (const int*)d_in[2];
    const float* w1  = (const float*)d_in[3];
    const float* b1  = (const float*)d_in[4];
    const float* w2  = (const float*)d_in[5];
    const float* b2  = (const float*)d_in[6];
    const float* w3  = (const float*)d_in[7];
    const float* b3  = (const float*)d_in[8];
    float* out = (float*)d_out;

    char* ws = (char*)d_ws;
    size_t off = 0;
    // --- zeroed region (one small memset, ~0.55 MB) ---
    int* binCount = (int*)(ws + off);          off += 4096;                  // NB ints, padded
    float* h_sum  = (float*)(ws + off);        off += (size_t)NG * 16 * 4;
    unsigned int* h_max = (unsigned int*)(ws + off); off += (size_t)NG * 16 * 4;
    int* cnt      = (int*)(ws + off);          off += (size_t)NG * 4;
    size_t zero_bytes = off;
    // --- non-zeroed scratch ---
    int* binStart = (int*)(ws + off);          off += 4096;                  // NB+1 ints
    int* binCursor= (int*)(ws + off);          off += 4096;                  // NB ints
    float* sx     = (float*)(ws + off);        off += (size_t)NE * 3 * 4;    // 60 MB
    unsigned short* srow = (unsigned short*)(ws + off); off += (size_t)NE * 2; // 10 MB

    hipMemsetAsync(d_ws, 0, zero_bytes, stream);

    bin_hist_k<<<BIN_BLOCKS, 256, 0, stream>>>(ei, binCount);
    bin_scan_k<<<1, 1024, 0, stream>>>(binCount, binStart, binCursor);
    bin_scatter_k<<<BIN_BLOCKS, 256, 0, stream>>>(ei, ei + NE, x, binCursor, sx, srow);
    bucket_agg_k<<<NB, 256, 1024 * 17 * 4 + 1024 * 4, stream>>>(
        sx, srow, binStart, bat, w1, b1, w2, b2, h_sum, h_max, cnt);
    out_k<<<(NG + 255) / 256, 256, 0, stream>>>(h_sum, h_max, cnt, w3, b3, out);
}

// Round 6
// 735.408 us; speedup vs baseline: 1.0016x; 1.0016x over previous
//
#include <hip/hip_runtime.h>
#include <hip/hip_bf16.h>

static constexpr int NN = 1000000;   // nodes
static constexpr int NE = 5000000;   // edges
static constexpr int NG = 4096;      // graphs
static constexpr int BIN_SH = 9;                      // 512 nodes per bin
static constexpr int BIN_SZ = 1 << BIN_SH;
static constexpr int NB = (NN + BIN_SZ - 1) >> BIN_SH;   // 1954 (last bin = 64 nodes, %64==0)
static constexpr int EPB = 16384;                     // edges per block for binning passes
static constexpr int BIN_BLOCKS = (NE + EPB - 1) / EPB;  // 306

// transform(x) == tanh(x) for finite x (nan_to_num / clip are no-ops on tanh output)
__device__ __forceinline__ float fast_tanh(float x) {
    x = fminf(fmaxf(x, -10.0f), 10.0f);
    float e = __expf(2.0f * x);
    return (e - 1.0f) / (e + 1.0f);
}

// ---- Pass 1: per-bin edge counts (LDS histogram, 1 global atomic per block-bin) ----
__global__ __launch_bounds__(256) void bin_hist_k(
    const int* __restrict__ row, int* __restrict__ binCount)
{
    __shared__ int hist[NB];
    for (int i = threadIdx.x; i < NB; i += 256) hist[i] = 0;
    __syncthreads();
    int base = blockIdx.x * EPB;
#pragma unroll 4
    for (int k = 0; k < EPB / 256; ++k) {
        int e = base + k * 256 + threadIdx.x;
        if (e < NE) atomicAdd(&hist[row[e] >> BIN_SH], 1);
    }
    __syncthreads();
    for (int i = threadIdx.x; i < NB; i += 256) {
        int c = hist[i];
        if (c) atomicAdd(&binCount[i], c);
    }
}

// ---- Pass 2: exclusive scan of binCount (NB<=2048) -> binStart, binCursor ----
__global__ __launch_bounds__(1024) void bin_scan_k(
    const int* __restrict__ binCount, int* __restrict__ binStart, int* __restrict__ binCursor)
{
    __shared__ int s[1024];
    int t = threadIdx.x;
    int i0 = 2 * t, i1 = 2 * t + 1;
    int v0 = (i0 < NB) ? binCount[i0] : 0;
    int v1 = (i1 < NB) ? binCount[i1] : 0;
    int tv = v0 + v1;
    s[t] = tv;
    __syncthreads();
    for (int off = 1; off < 1024; off <<= 1) {
        int u = (t >= off) ? s[t - off] : 0;
        __syncthreads();
        s[t] += u;
        __syncthreads();
    }
    int ex = s[t] - tv;
    if (i0 < NB) { binStart[i0] = ex;      binCursor[i0] = ex; }
    if (i1 < NB) { binStart[i1] = ex + v0; binCursor[i1] = ex + v0; }
    if (t == 0) binStart[NB] = NE;
}

// ---- Pass 3: scatter x-triplet + local row into bin-grouped order ----
__global__ __launch_bounds__(256) void bin_scatter_k(
    const int* __restrict__ row, const int* __restrict__ col,
    const float* __restrict__ x, int* __restrict__ binCursor,
    float* __restrict__ sx, unsigned short* __restrict__ srow)
{
    __shared__ int hist[NB];
    for (int i = threadIdx.x; i < NB; i += 256) hist[i] = 0;
    __syncthreads();
    int base = blockIdx.x * EPB;
#pragma unroll 4
    for (int k = 0; k < EPB / 256; ++k) {
        int e = base + k * 256 + threadIdx.x;
        if (e < NE) atomicAdd(&hist[row[e] >> BIN_SH], 1);
    }
    __syncthreads();
    // hist[bin] becomes this block's global write cursor for that bin
    for (int i = threadIdx.x; i < NB; i += 256) {
        int c = hist[i];
        hist[i] = c ? atomicAdd(&binCursor[i], c) : 0;
    }
    __syncthreads();
#pragma unroll 4
    for (int k = 0; k < EPB / 256; ++k) {
        int e = base + k * 256 + threadIdx.x;
        if (e >= NE) continue;
        int r = row[e];
        int c = col[e];
        int pos = atomicAdd(&hist[r >> BIN_SH], 1);
        float x0 = x[3 * c + 0], x1 = x[3 * c + 1], x2 = x[3 * c + 2];
        size_t p3 = 3 * (size_t)pos;
        sx[p3 + 0] = x0; sx[p3 + 1] = x1; sx[p3 + 2] = x2;
        srow[pos] = (unsigned short)(r & (BIN_SZ - 1));
    }
}

// ---- Pass 4: per-bucket LDS aggregation + MLP2 + segmented-scan pooling ----
// LDS = 512*17*4 (agg, padded) + 512*4 (degs) = 36 KB -> 4 blocks/CU.
__global__ __launch_bounds__(256) void bucket_agg_k(
    const float* __restrict__ sx,
    const unsigned short* __restrict__ srow,
    const int* __restrict__ binStart,
    const int* __restrict__ batch,
    const float* __restrict__ w1,   // [3,16]
    const float* __restrict__ b1,   // [16]
    const float* __restrict__ w2,   // [16,16]
    const float* __restrict__ b2,   // [16]
    float* __restrict__ h_sum,      // [NG,16]
    unsigned int* __restrict__ h_max, // [NG,16] monotone-encoded
    int* __restrict__ cnt)          // [NG]
{
    extern __shared__ char smem[];
    float* agg = (float*)smem;                          // [BIN_SZ][17] padded
    int* degs  = (int*)(smem + BIN_SZ * 17 * 4);        // [BIN_SZ]

    for (int i = threadIdx.x; i < BIN_SZ * 17; i += 256) agg[i] = 0.0f;
    for (int i = threadIdx.x; i < BIN_SZ; i += 256) degs[i] = 0;
    __syncthreads();

    int b = blockIdx.x;
    int nodeBase = b << BIN_SH;
    int nNodes = min(BIN_SZ, NN - nodeBase);            // 512, or 64 for last bin (%64==0)
    int es = binStart[b], ee = binStart[b + 1];

    // edge phase: recompute h1 on the fly, native ds_add_f32 (fire-and-forget)
    for (int i = es + threadIdx.x; i < ee; i += 256) {
        size_t p3 = 3 * (size_t)i;
        float x0 = sx[p3 + 0], x1 = sx[p3 + 1], x2 = sx[p3 + 2];
        int rl = srow[i];
        atomicAdd(&degs[rl], 1);                        // int LDS atomic: native
        float* ar = &agg[rl * 17];
#pragma unroll
        for (int j = 0; j < 16; ++j) {
            float v = fmaf(x2, w1[32 + j], fmaf(x1, w1[16 + j], fmaf(x0, w1[j], b1[j])));
            unsafeAtomicAdd(&ar[j], fast_tanh(v));      // ds_add_f32, not a CAS loop
        }
    }
    __syncthreads();

    // node phase: normalize, MLP2, tanh, segmented wave reduction over sorted batch
    for (int nb = 0; nb < nNodes; nb += 256) {
        int node = nb + threadIdx.x;
        if (node >= nNodes) continue;                   // wave-uniform (nNodes % 64 == 0)
        int dg = degs[node];
        float inv = 1.0f / fmaxf((float)dg, 1.0f);
        float s[16];
#pragma unroll
        for (int j = 0; j < 16; ++j) s[j] = b2[j];
#pragma unroll
        for (int k = 0; k < 16; ++k) {
            float a = agg[node * 17 + k] * inv;
#pragma unroll
            for (int j = 0; j < 16; ++j) s[j] = fmaf(a, w2[16 * k + j], s[j]);
        }
        float m[16];
#pragma unroll
        for (int j = 0; j < 16; ++j) { s[j] = fast_tanh(s[j]); m[j] = s[j]; }

        int g = batch[nodeBase + node];
        int lane = threadIdx.x & 63;
        int gp = __shfl_up(g, 1);
        int head = (lane == 0) || (g != gp);
        unsigned long long hm = __ballot(head != 0);

        int f = head;
#pragma unroll
        for (int off = 1; off < 64; off <<= 1) {
            int fu = __shfl_up(f, off);
            bool take = (lane >= off) && (f == 0);
#pragma unroll
            for (int j = 0; j < 16; ++j) {
                float su = __shfl_up(s[j], off);
                float mu = __shfl_up(m[j], off);
                if (take) { s[j] += su; m[j] = fmaxf(m[j], mu); }
            }
            if (lane >= off) f |= fu;
        }

        int hnext = __shfl_down(head, 1);
        bool is_last = (lane == 63) || (hnext != 0);
        if (is_last) {
            unsigned long long below = hm & (~0ULL >> (63 - lane));
            int start = 63 - __clzll(below);
            int seglen = lane - start + 1;
#pragma unroll
            for (int j = 0; j < 16; ++j) {
                unsafeAtomicAdd(&h_sum[16 * g + j], s[j]);
                atomicMax(&h_max[16 * g + j], __float_as_uint(m[j] + 2.0f));
            }
            atomicAdd(&cnt[g], seglen);
        }
    }
}

// ---- Pass 5: head ----
__global__ __launch_bounds__(256) void out_k(
    const float* __restrict__ h_sum,
    const unsigned int* __restrict__ h_max,
    const int* __restrict__ cnt,
    const float* __restrict__ w3,   // [32]
    const float* __restrict__ b3,   // [1]
    float* __restrict__ out)        // [NG]
{
    int g = blockIdx.x * 256 + threadIdx.x;
    if (g >= NG) return;
    float invc = 1.0f / fmaxf((float)cnt[g], 1.0f);
    float acc = b3[0];
#pragma unroll
    for (int j = 0; j < 16; ++j) {
        float mean = h_sum[16 * g + j] * invc;
        unsigned int e = h_max[16 * g + j];
        float mx = (e == 0u) ? 0.0f : (__uint_as_float(e) - 2.0f);
        acc = fmaf(mean, w3[j], fmaf(mx, w3[16 + j], acc));
    }
    out[g] = 1.0f / (1.0f + __expf(-acc));
}

extern "C" void kernel_launch(void* const* d_in, const int* in_sizes, int n_in,
                              void* d_out, int out_size, void* d_ws, size_t ws_size,
                              hipStream_t stream)
{
    const float* x   = (const float*)d_in[0];
    const int*   ei  = (const int*)d_in[1];   // row = ei, col = ei + NE
    const int*   bat = (const int*)d_in[2];
    const float* w1  = (const float*)d_in[3];
    const float* b1  = (const float*)d_in[4];
    const float* w2  = (const float*)d_in[5];
    const float* b2  = (const float*)d_in[6];
    const float* w3  = (const float*)d_in[7];
    const float* b3  = (const float*)d_in[8];
    float* out = (float*)d_out;

    char* ws = (char*)d_ws;
    size_t off = 0;
    // --- zeroed region (one small memset, ~0.57 MB) ---
    int* binCount = (int*)(ws + off);          off += 8192;                  // NB ints, padded
    float* h_sum  = (float*)(ws + off);        off += (size_t)NG * 16 * 4;
    unsigned int* h_max = (unsigned int*)(ws + off); off += (size_t)NG * 16 * 4;
    int* cnt      = (int*)(ws + off);          off += (size_t)NG * 4;
    size_t zero_bytes = off;
    // --- non-zeroed scratch ---
    int* binStart = (int*)(ws + off);          off += 8192;                  // NB+1 ints
    int* binCursor= (int*)(ws + off);          off += 8192;                  // NB ints
    float* sx     = (float*)(ws + off);        off += (size_t)NE * 3 * 4;    // 60 MB
    unsigned short* srow = (unsigned short*)(ws + off); off += (size_t)NE * 2; // 10 MB

    hipMemsetAsync(d_ws, 0, zero_bytes, stream);

    bin_hist_k<<<BIN_BLOCKS, 256, 0, stream>>>(ei, binCount);
    bin_scan_k<<<1, 1024, 0, stream>>>(binCount, binStart, binCursor);
    bin_scatter_k<<<BIN_BLOCKS, 256, 0, stream>>>(ei, ei + NE, x, binCursor, sx, srow);
    bucket_agg_k<<<NB, 256, BIN_SZ * 17 * 4 + BIN_SZ * 4, stream>>>(
        sx, srow, binStart, bat, w1, b1, w2, b2, h_sum, h_max, cnt);
    out_k<<<(NG + 255) / 256, 256, 0, stream>>>(h_sum, h_max, cnt, w3, b3, out);
}

// Round 7
// 280.678 us; speedup vs baseline: 2.6243x; 2.6201x over previous
//
#include <hip/hip_runtime.h>
#include <hip/hip_bf16.h>

static constexpr int NN = 1000000;   // nodes
static constexpr int NE = 5000000;   // edges
static constexpr int NG = 4096;      // graphs
static constexpr int BIN_SH = 8;                      // 256 nodes per bin
static constexpr int BIN_SZ = 1 << BIN_SH;            // 256
static constexpr int NB = (NN + BIN_SZ - 1) >> BIN_SH;   // 3907 (last bin = 64 nodes, %64==0)
static constexpr int EPB = 16384;                     // edges per block for binning passes
static constexpr int BIN_BLOCKS = (NE + EPB - 1) / EPB;  // 306
static constexpr int CHUNK = 2048;                    // edges per LDS chunk in bucket_agg

// transform(x) == tanh(x) for finite x (nan_to_num / clip are no-ops on tanh output)
__device__ __forceinline__ float fast_tanh(float x) {
    x = fminf(fmaxf(x, -10.0f), 10.0f);
    float e = __expf(2.0f * x);
    return 1.0f - 2.0f * __fdividef(1.0f, e + 1.0f);
}

// ---- Pass 1: per-bin edge counts (LDS histogram, 1 global atomic per block-bin) ----
__global__ __launch_bounds__(256) void bin_hist_k(
    const int* __restrict__ row, int* __restrict__ binCount)
{
    __shared__ int hist[NB];          // 15.6 KB
    for (int i = threadIdx.x; i < NB; i += 256) hist[i] = 0;
    __syncthreads();
    int base = blockIdx.x * EPB;
#pragma unroll 4
    for (int k = 0; k < EPB / 256; ++k) {
        int e = base + k * 256 + threadIdx.x;
        if (e < NE) atomicAdd(&hist[row[e] >> BIN_SH], 1);
    }
    __syncthreads();
    for (int i = threadIdx.x; i < NB; i += 256) {
        int c = hist[i];
        if (c) atomicAdd(&binCount[i], c);
    }
}

// ---- Pass 2: exclusive scan of binCount (NB<=4096) -> binStart, binCursor ----
__global__ __launch_bounds__(1024) void bin_scan_k(
    const int* __restrict__ binCount, int* __restrict__ binStart, int* __restrict__ binCursor)
{
    __shared__ int s[1024];
    int t = threadIdx.x;
    int base = t * 4;
    int v[4];
    int tv = 0;
#pragma unroll
    for (int k = 0; k < 4; ++k) {
        v[k] = (base + k < NB) ? binCount[base + k] : 0;
        tv += v[k];
    }
    s[t] = tv;
    __syncthreads();
    for (int off = 1; off < 1024; off <<= 1) {
        int u = (t >= off) ? s[t - off] : 0;
        __syncthreads();
        s[t] += u;
        __syncthreads();
    }
    int ex = s[t] - tv;
#pragma unroll
    for (int k = 0; k < 4; ++k) {
        if (base + k < NB) { binStart[base + k] = ex; binCursor[base + k] = ex; }
        ex += v[k];
    }
    if (t == 0) binStart[NB] = NE;
}

// ---- Pass 3: scatter packed (rl, col) into bin-grouped order ----
// pack = (local_row << 20) | col   (col < 2^20, local_row < 2^8)
__global__ __launch_bounds__(256) void bin_scatter_k(
    const int* __restrict__ row, const int* __restrict__ col,
    int* __restrict__ binCursor, unsigned int* __restrict__ pack)
{
    __shared__ int hist[NB];
    for (int i = threadIdx.x; i < NB; i += 256) hist[i] = 0;
    __syncthreads();
    int base = blockIdx.x * EPB;
#pragma unroll 4
    for (int k = 0; k < EPB / 256; ++k) {
        int e = base + k * 256 + threadIdx.x;
        if (e < NE) atomicAdd(&hist[row[e] >> BIN_SH], 1);
    }
    __syncthreads();
    // hist[bin] becomes this block's global write cursor for that bin
    for (int i = threadIdx.x; i < NB; i += 256) {
        int c = hist[i];
        hist[i] = c ? atomicAdd(&binCursor[i], c) : 0;
    }
    __syncthreads();
#pragma unroll 4
    for (int k = 0; k < EPB / 256; ++k) {
        int e = base + k * 256 + threadIdx.x;
        if (e >= NE) continue;
        int r = row[e];
        int c = col[e];
        int pos = atomicAdd(&hist[r >> BIN_SH], 1);
        pack[pos] = ((unsigned int)(r & (BIN_SZ - 1)) << 20) | (unsigned int)c;
    }
}

// ---- Pass 4: per-bin chunked counting-sort + REGISTER accumulation + MLP2 + pooling ----
// No f32 LDS atomics: edges sorted into LDS per-node runs, each thread owns one
// node and accumulates its 16 features in registers.
__global__ __launch_bounds__(256) void bucket_agg_k(
    const unsigned int* __restrict__ pack,
    const int* __restrict__ binStart,
    const float* __restrict__ x,
    const int* __restrict__ batch,
    const float* __restrict__ w1,   // [3,16]
    const float* __restrict__ b1,   // [16]
    const float* __restrict__ w2,   // [16,16]
    const float* __restrict__ b2,   // [16]
    float* __restrict__ h_sum,      // [NG,16]
    unsigned int* __restrict__ h_max, // [NG,16] monotone-encoded
    int* __restrict__ cnt)          // [NG]
{
    __shared__ float pay[CHUNK * 3];   // 24 KB sorted x-triplets
    __shared__ int scnt[BIN_SZ];       // hist -> cursor
    __shared__ int sstart[BIN_SZ];     // exclusive starts

    int tid = threadIdx.x;
    int b = blockIdx.x;
    int nodeBase = b << BIN_SH;
    int nNodes = min(BIN_SZ, NN - nodeBase);   // 256, or 64 for last bin (%64==0)
    int es = binStart[b], ee = binStart[b + 1];

    float acc[16];
#pragma unroll
    for (int j = 0; j < 16; ++j) acc[j] = 0.0f;
    int dg = 0;

    for (int cs = es; cs < ee; cs += CHUNK) {
        int m = min(CHUNK, ee - cs);
        scnt[tid] = 0;
        __syncthreads();

        // load up to 8 edges/thread: pack + x-gather (8-deep ILP), LDS hist
        float xs0[8], xs1[8], xs2[8];
        int rl8[8];
#pragma unroll
        for (int k = 0; k < 8; ++k) {
            int e = cs + k * 256 + tid;
            bool val = (e < cs + m);
            unsigned int p = val ? pack[e] : 0u;
            int c = (int)(p & 0xFFFFFu);
            rl8[k] = val ? (int)(p >> 20) : -1;
            xs0[k] = x[3 * c + 0];
            xs1[k] = x[3 * c + 1];
            xs2[k] = x[3 * c + 2];
            if (val) atomicAdd(&scnt[rl8[k]], 1);   // no-return ds_add
        }
        __syncthreads();

        // exclusive scan scnt -> sstart; scnt becomes the scatter cursor
        int v = scnt[tid];
        sstart[tid] = v;
        __syncthreads();
        for (int off = 1; off < 256; off <<= 1) {
            int u = (tid >= off) ? sstart[tid - off] : 0;
            __syncthreads();
            sstart[tid] += u;
            __syncthreads();
        }
        int ex = sstart[tid] - v;    // own-element only: no cross-thread hazard
        sstart[tid] = ex;
        scnt[tid] = ex;
        __syncthreads();

        // counting-sort scatter of payloads into per-node runs
#pragma unroll
        for (int k = 0; k < 8; ++k) {
            if (rl8[k] >= 0) {
                int pos = atomicAdd(&scnt[rl8[k]], 1);   // returning ds_add_rtn
                pay[3 * pos + 0] = xs0[k];
                pay[3 * pos + 1] = xs1[k];
                pay[3 * pos + 2] = xs2[k];
            }
        }
        __syncthreads();

        // owner accumulation: thread tid owns node tid (register accumulators)
        if (tid < nNodes) {
            int s0 = sstart[tid];
            int e0 = (tid < 255) ? sstart[tid + 1] : m;
            dg += e0 - s0;
            for (int e = s0; e < e0; ++e) {
                float x0 = pay[3 * e + 0], x1 = pay[3 * e + 1], x2 = pay[3 * e + 2];
#pragma unroll
                for (int j = 0; j < 16; ++j) {
                    float vv = fmaf(x2, w1[32 + j], fmaf(x1, w1[16 + j], fmaf(x0, w1[j], b1[j])));
                    acc[j] += fast_tanh(vv);
                }
            }
        }
        __syncthreads();   // before next chunk reuses scnt/pay
    }

    // node phase: normalize, MLP2, tanh, segmented wave reduction over sorted batch
    if (tid < nNodes) {                       // wave-uniform (nNodes % 64 == 0)
        float inv = 1.0f / fmaxf((float)dg, 1.0f);
        float s[16];
#pragma unroll
        for (int j = 0; j < 16; ++j) s[j] = b2[j];
#pragma unroll
        for (int k = 0; k < 16; ++k) {
            float a = acc[k] * inv;
#pragma unroll
            for (int j = 0; j < 16; ++j) s[j] = fmaf(a, w2[16 * k + j], s[j]);
        }
        float m[16];
#pragma unroll
        for (int j = 0; j < 16; ++j) { s[j] = fast_tanh(s[j]); m[j] = s[j]; }

        int g = batch[nodeBase + tid];
        int lane = threadIdx.x & 63;
        int gp = __shfl_up(g, 1);
        int head = (lane == 0) || (g != gp);
        unsigned long long hm = __ballot(head != 0);

        int f = head;
#pragma unroll
        for (int off = 1; off < 64; off <<= 1) {
            int fu = __shfl_up(f, off);
            bool take = (lane >= off) && (f == 0);
#pragma unroll
            for (int j = 0; j < 16; ++j) {
                float su = __shfl_up(s[j], off);
                float mu = __shfl_up(m[j], off);
                if (take) { s[j] += su; m[j] = fmaxf(m[j], mu); }
            }
            if (lane >= off) f |= fu;
        }

        int hnext = __shfl_down(head, 1);
        bool is_last = (lane == 63) || (hnext != 0);
        if (is_last) {
            unsigned long long below = hm & (~0ULL >> (63 - lane));
            int start = 63 - __clzll(below);
            int seglen = lane - start + 1;
#pragma unroll
            for (int j = 0; j < 16; ++j) {
                unsafeAtomicAdd(&h_sum[16 * g + j], s[j]);
                atomicMax(&h_max[16 * g + j], __float_as_uint(m[j] + 2.0f));
            }
            atomicAdd(&cnt[g], seglen);
        }
    }
}

// ---- Pass 5: head ----
__global__ __launch_bounds__(256) void out_k(
    const float* __restrict__ h_sum,
    const unsigned int* __restrict__ h_max,
    const int* __restrict__ cnt,
    const float* __restrict__ w3,   // [32]
    const float* __restrict__ b3,   // [1]
    float* __restrict__ out)        // [NG]
{
    int g = blockIdx.x * 256 + threadIdx.x;
    if (g >= NG) return;
    float invc = 1.0f / fmaxf((float)cnt[g], 1.0f);
    float acc = b3[0];
#pragma unroll
    for (int j = 0; j < 16; ++j) {
        float mean = h_sum[16 * g + j] * invc;
        unsigned int e = h_max[16 * g + j];
        float mx = (e == 0u) ? 0.0f : (__uint_as_float(e) - 2.0f);
        acc = fmaf(mean, w3[j], fmaf(mx, w3[16 + j], acc));
    }
    out[g] = 1.0f / (1.0f + __expf(-acc));
}

extern "C" void kernel_launch(void* const* d_in, const int* in_sizes, int n_in,
                              void* d_out, int out_size, void* d_ws, size_t ws_size,
                              hipStream_t stream)
{
    const float* x   = (const float*)d_in[0];
    const int*   ei  = (const int*)d_in[1];   // row = ei, col = ei + NE
    const int*   bat = (const int*)d_in[2];
    const float* w1  = (const float*)d_in[3];
    const float* b1  = (const float*)d_in[4];
    const float* w2  = (const float*)d_in[5];
    const float* b2  = (const float*)d_in[6];
    const float* w3  = (const float*)d_in[7];
    const float* b3  = (const float*)d_in[8];
    float* out = (float*)d_out;

    char* ws = (char*)d_ws;
    size_t off = 0;
    // --- zeroed region (one small memset, ~0.55 MB) ---
    int* binCount = (int*)(ws + off);          off += 16384;                 // NB ints, padded
    float* h_sum  = (float*)(ws + off);        off += (size_t)NG * 16 * 4;
    unsigned int* h_max = (unsigned int*)(ws + off); off += (size_t)NG * 16 * 4;
    int* cnt      = (int*)(ws + off);          off += (size_t)NG * 4;
    size_t zero_bytes = off;
    // --- non-zeroed scratch ---
    int* binStart = (int*)(ws + off);          off += 16384;                 // NB+1 ints
    int* binCursor= (int*)(ws + off);          off += 16384;                 // NB ints
    unsigned int* pack = (unsigned int*)(ws + off); off += (size_t)NE * 4;   // 20 MB

    hipMemsetAsync(d_ws, 0, zero_bytes, stream);

    bin_hist_k<<<BIN_BLOCKS, 256, 0, stream>>>(ei, binCount);
    bin_scan_k<<<1, 1024, 0, stream>>>(binCount, binStart, binCursor);
    bin_scatter_k<<<BIN_BLOCKS, 256, 0, stream>>>(ei, ei + NE, binCursor, pack);
    bucket_agg_k<<<NB, 256, 0, stream>>>(pack, binStart, x, bat,
                                         w1, b1, w2, b2, h_sum, h_max, cnt);
    out_k<<<(NG + 255) / 256, 256, 0, stream>>>(h_sum, h_max, cnt, w3, b3, out);
}